// Round 1
// baseline (437.070 us; speedup 1.0000x reference)
//
#include <hip/hip_runtime.h>
#include <cstdint>

#define IN_C 128
#define HID 64
#define OUT_C 64
#define EPS_LN 1e-5f
#define NEG_SLOPE 0.01f

// broadcast lane l's value to all lanes (wave-uniform result)
__device__ __forceinline__ float bcast(float v, int l) {
    return __int_as_float(__builtin_amdgcn_readlane(__float_as_int(v), l));
}

// order-preserving map float -> uint32 (ascending float => ascending uint)
__device__ __forceinline__ unsigned enc_f32(float f) {
    unsigned u = __float_as_uint(f);
    return (u & 0x80000000u) ? ~u : (u | 0x80000000u);
}

// ---------------------------------------------------------------------------
// Kernel 1: h = LayerNorm(LeakyReLU(x @ W1^T + b1)) stored ENCODED (sortable u32)
// one wave per node (4 nodes/wave sequential), W1 staged transposed+packed in LDS
// ---------------------------------------------------------------------------
__global__ __launch_bounds__(256) void mlp_ln_kernel(
    const float* __restrict__ x, const float* __restrict__ W1,
    const float* __restrict__ b1, const float* __restrict__ gamma,
    const float* __restrict__ beta, unsigned* __restrict__ h_enc, int N)
{
    // w1q[k4][o] = float4 {W1[o][4k4..4k4+3]}, row stride 65 float4s (pad kills bank conflicts)
    __shared__ __align__(16) float w1q[32 * 260];

    for (int m = threadIdx.x; m < HID * IN_C; m += 256) {
        int o = m >> 7;          // 0..63
        int k = m & 127;         // 0..127
        w1q[(k >> 2) * 260 + (o << 2) + (k & 3)] = W1[m];
    }
    __syncthreads();

    const int lane = threadIdx.x & 63;
    const int wid  = threadIdx.x >> 6;   // 0..3

    const float b1l = b1[lane];
    const float gl  = gamma[lane];
    const float bl  = beta[lane];

    for (int t = 0; t < 4; ++t) {
        int node = (blockIdx.x * 4 + wid) * 4 + t;
        if (node >= N) break;

        // wave loads x row: 2 coalesced 256B segments
        float x0 = x[(size_t)node * IN_C + lane];
        float x1 = x[(size_t)node * IN_C + 64 + lane];

        float acc = b1l;
#pragma unroll
        for (int k4 = 0; k4 < 16; ++k4) {
            float4 w = *reinterpret_cast<const float4*>(&w1q[k4 * 260 + (lane << 2)]);
            acc = fmaf(bcast(x0, 4 * k4 + 0), w.x, acc);
            acc = fmaf(bcast(x0, 4 * k4 + 1), w.y, acc);
            acc = fmaf(bcast(x0, 4 * k4 + 2), w.z, acc);
            acc = fmaf(bcast(x0, 4 * k4 + 3), w.w, acc);
        }
#pragma unroll
        for (int k4 = 16; k4 < 32; ++k4) {
            float4 w = *reinterpret_cast<const float4*>(&w1q[k4 * 260 + (lane << 2)]);
            int kb = 4 * (k4 - 16);
            acc = fmaf(bcast(x1, kb + 0), w.x, acc);
            acc = fmaf(bcast(x1, kb + 1), w.y, acc);
            acc = fmaf(bcast(x1, kb + 2), w.z, acc);
            acc = fmaf(bcast(x1, kb + 3), w.w, acc);
        }

        // LeakyReLU
        float h = acc > 0.f ? acc : acc * NEG_SLOPE;

        // LayerNorm over the 64 lanes (wave butterfly reductions)
        float s = h;
#pragma unroll
        for (int off = 32; off > 0; off >>= 1) s += __shfl_xor(s, off, 64);
        float mu = s * (1.f / 64.f);
        float d = h - mu;
        float q = d * d;
#pragma unroll
        for (int off = 32; off > 0; off >>= 1) q += __shfl_xor(q, off, 64);
        float var = q * (1.f / 64.f);
        float hn = d * rsqrtf(var + EPS_LN) * gl + bl;

        h_enc[(size_t)node * HID + lane] = enc_f32(hn);
    }
}

// ---------------------------------------------------------------------------
// Kernel 2: scatter-min over edges. One wave per edge; lane = channel.
// agg pre-initialized to 0xFFFFFFFF (encoded "above +inf") via hipMemsetAsync.
// ---------------------------------------------------------------------------
__global__ __launch_bounds__(256) void scatter_min_kernel(
    const int* __restrict__ ei, const unsigned* __restrict__ h_enc,
    unsigned* __restrict__ agg, int E)
{
    int w = (int)((blockIdx.x * 256 + threadIdx.x) >> 6);
    int lane = threadIdx.x & 63;
    if (w < E) {
        int src = ei[w];
        int dst = ei[E + w];
        unsigned key = h_enc[(size_t)src * HID + lane];
        atomicMin(&agg[(size_t)dst * HID + lane], key);  // no-return umin
    }
}

// ---------------------------------------------------------------------------
// Kernel 3: out = (decode(agg), key>=enc(+inf) -> 0) @ W2^T + b2
// ---------------------------------------------------------------------------
__global__ __launch_bounds__(256) void out_gemm_kernel(
    const unsigned* __restrict__ agg, const float* __restrict__ W2,
    const float* __restrict__ b2, float* __restrict__ out, int N)
{
    __shared__ float w2t[HID * 65];  // w2t[j*65+o] = W2[o][j]

    for (int m = threadIdx.x; m < OUT_C * HID; m += 256) {
        int o = m >> 6;
        int j = m & 63;
        w2t[j * 65 + o] = W2[m];
    }
    __syncthreads();

    const int lane = threadIdx.x & 63;
    const int wid  = threadIdx.x >> 6;
    const float b2l = b2[lane];

    for (int t = 0; t < 4; ++t) {
        int node = (blockIdx.x * 4 + wid) * 4 + t;
        if (node >= N) break;

        unsigned key = agg[(size_t)node * HID + lane];
        float a;
        if (key >= 0xFF800000u) {        // >= encode(+inf): no-edge init or inf
            a = 0.f;
        } else {
            unsigned u = (key & 0x80000000u) ? (key ^ 0x80000000u) : ~key;
            a = __uint_as_float(u);
        }

        float acc = b2l;
#pragma unroll
        for (int j = 0; j < 64; ++j) {
            acc = fmaf(bcast(a, j), w2t[j * 65 + lane], acc);
        }
        out[(size_t)node * OUT_C + lane] = acc;
    }
}

// ---------------------------------------------------------------------------
extern "C" void kernel_launch(void* const* d_in, const int* in_sizes, int n_in,
                              void* d_out, int out_size, void* d_ws, size_t ws_size,
                              hipStream_t stream) {
    const float* x     = (const float*)d_in[0];
    // d_in[1] = x_e (unused)
    const int*   ei    = (const int*)d_in[2];
    const float* W1    = (const float*)d_in[3];
    const float* b1    = (const float*)d_in[4];
    const float* gamma = (const float*)d_in[5];
    const float* beta  = (const float*)d_in[6];
    const float* W2    = (const float*)d_in[7];
    const float* b2    = (const float*)d_in[8];
    float* out = (float*)d_out;

    const int N = in_sizes[0] / IN_C;
    const int E = in_sizes[2] / 2;

    unsigned* h_enc = (unsigned*)d_ws;                    // N*HID u32 = 12.8 MB
    unsigned* agg   = h_enc + (size_t)N * HID;            // N*HID u32 = 12.8 MB

    // init agg to 0xFFFFFFFF == encoded "greater than +inf"
    hipMemsetAsync(agg, 0xFF, (size_t)N * HID * sizeof(unsigned), stream);

    const int node_blocks = (N + 15) / 16;   // 16 nodes per 256-thread block
    mlp_ln_kernel<<<node_blocks, 256, 0, stream>>>(x, W1, b1, gamma, beta, h_enc, N);

    const int edge_blocks = (E + 3) / 4;     // 4 edges (waves) per block
    scatter_min_kernel<<<edge_blocks, 256, 0, stream>>>(ei, h_enc, agg, E);

    out_gemm_kernel<<<node_blocks, 256, 0, stream>>>(agg, W2, b2, out, N);
}